// Round 8
// baseline (96.973 us; speedup 1.0000x reference)
//
#include <hip/hip_runtime.h>
#include <hip/hip_bf16.h>
#include <math.h>

#define B_   8
#define N_   1024
#define FIN  128
#define FOUT 128
#define H_   8
#define NEG  0.2f

typedef __attribute__((ext_vector_type(4))) float f32x4;
typedef __attribute__((ext_vector_type(8))) short s16x8;

static __device__ __forceinline__ unsigned short f2bf(float f) {
    unsigned int u = __float_as_uint(f);
    unsigned int r = (u + 0x7fffu + ((u >> 16) & 1u)) >> 16;   // RNE (software)
    return (unsigned short)r;
}

static __device__ __forceinline__ unsigned short f2bf_hw(float f) {
    union { __hip_bfloat16 b; unsigned short u; } cv;
    cv.b = __float2bfloat16(f);
    return cv.u;
}

// async global->LDS, 16B per lane, wave-uniform LDS base + lane*16
static __device__ __forceinline__ void gll16(const unsigned short* g, unsigned short* l) {
    __builtin_amdgcn_global_load_lds(
        (const __attribute__((address_space(1))) unsigned int*)g,
        (__attribute__((address_space(3))) unsigned int*)l, 16, 0, 0);
}

// ---------------- K0: biasm[i][j] = adj ? bias : -inf  (mask folded into bias) -------
__global__ __launch_bounds__(256) void k_bias(const int* __restrict__ adj,
                                              const float* __restrict__ bias,
                                              float* __restrict__ biasm) {
    const int base = (blockIdx.x * 256 + threadIdx.x) * 4;
    int4   av = *(const int4*)&adj[base];
    float4 bv = *(const float4*)&bias[base];
    const float NINF = -__builtin_inff();
    float4 r;
    r.x = av.x ? bv.x : NINF;
    r.y = av.y ? bv.y : NINF;
    r.z = av.z ? bv.z : NINF;
    r.w = av.w ? bv.w : NINF;
    *(float4*)&biasm[base] = r;
}

// ---------------- K0b: W [H][FIN][FOUT] f32  ->  WT [H][FOUT][FIN] bf16 --------------
__global__ __launch_bounds__(256) void k_wt(const float* __restrict__ W,
                                            unsigned short* __restrict__ WT) {
    const int hd = blockIdx.x;
    const int t  = threadIdx.x;
    const int fo  = t >> 1;
    const int fi0 = (t & 1) * 64;
    const float* src = W + (size_t)hd * FIN * FOUT;
    unsigned short* dst = WT + ((size_t)hd * FOUT + fo) * FIN + fi0;
#pragma unroll
    for (int c = 0; c < 8; ++c) {
        s16x8 v;
#pragma unroll
        for (int u = 0; u < 8; ++u)
            v[u] = (short)f2bf(src[(size_t)(fi0 + c * 8 + u) * FOUT + fo]);
        *(s16x8*)(dst + c * 8) = v;
    }
}

// ---------------- K1: h' via bf16 MFMA + transpose-to-bf16 + s1/s2 epilogue ----------
#define PADK 132
union SmemK1 {
    struct {
        unsigned short A[64 * PADK];
        unsigned short Bm[128 * PADK];
    } s;
    float tr[64 * PADK];
};

__global__ __launch_bounds__(256, 3) void k_hprime(const float* __restrict__ hsrc,
                                                   const unsigned short* __restrict__ WT,
                                                   const float* __restrict__ a,
                                                   unsigned short* __restrict__ hpT,
                                                   float* __restrict__ s1,
                                                   float* __restrict__ s2T) {
    __shared__ SmemK1 sm;
    const int t    = threadIdx.x;
    const int lane = t & 63;
    const int wave = t >> 6;
    const int bn0  = blockIdx.x * 64;
    const int hd   = blockIdx.y;

    {
        const int r = t >> 2, k0 = (t & 3) * 32;
        const float* src = hsrc + (size_t)(bn0 + r) * FIN + k0;
        unsigned short* dst = &sm.s.A[r * PADK + k0];
#pragma unroll
        for (int c = 0; c < 4; ++c) {
            float4 x = *(const float4*)&src[c * 8];
            float4 y = *(const float4*)&src[c * 8 + 4];
            s16x8 v;
            v[0] = (short)f2bf(x.x); v[1] = (short)f2bf(x.y);
            v[2] = (short)f2bf(x.z); v[3] = (short)f2bf(x.w);
            v[4] = (short)f2bf(y.x); v[5] = (short)f2bf(y.y);
            v[6] = (short)f2bf(y.z); v[7] = (short)f2bf(y.w);
            *(s16x8*)(dst + c * 8) = v;
        }
    }
    {
        const int r = t >> 1, k0 = (t & 1) * 64;
        const unsigned short* src = WT + ((size_t)hd * FOUT + r) * FIN + k0;
        unsigned short* dst = &sm.s.Bm[r * PADK + k0];
#pragma unroll
        for (int c = 0; c < 8; ++c)
            *(s16x8*)(dst + c * 8) = *(const s16x8*)(src + c * 8);
    }
    __syncthreads();

    const int wr   = wave * 16;
    const int arow = wr + (lane & 15);
    const int koff = (lane >> 4) * 8;
    f32x4 acc[8];
#pragma unroll
    for (int fc = 0; fc < 8; ++fc) acc[fc] = (f32x4){0.f, 0.f, 0.f, 0.f};
#pragma unroll
    for (int kk = 0; kk < 4; ++kk) {
        s16x8 av = *(const s16x8*)&sm.s.A[arow * PADK + kk * 32 + koff];
#pragma unroll
        for (int fc = 0; fc < 8; ++fc) {
            s16x8 bv = *(const s16x8*)&sm.s.Bm[(fc * 16 + (lane & 15)) * PADK + kk * 32 + koff];
            acc[fc] = __builtin_amdgcn_mfma_f32_16x16x32_bf16(av, bv, acc[fc], 0, 0, 0);
        }
    }
    __syncthreads();

#pragma unroll
    for (int fc = 0; fc < 8; ++fc)
#pragma unroll
        for (int r = 0; r < 4; ++r)
            sm.tr[(wr + (lane >> 4) * 4 + r) * PADK + fc * 16 + (lane & 15)] = acc[fc][r];
    __syncthreads();

    {
        const int f   = t >> 1;
        const int seg = (t & 1) * 32;
        const int b   = bn0 >> 10;
        const int n0  = bn0 & 1023;
        unsigned short* dst = hpT + (((size_t)(b * H_ + hd) * FOUT + f) * N_) + n0 + seg;
#pragma unroll
        for (int c = 0; c < 4; ++c) {
            s16x8 v;
#pragma unroll
            for (int u = 0; u < 8; ++u)
                v[u] = (short)f2bf(sm.tr[(seg + c * 8 + u) * PADK + f]);
            *(s16x8*)(dst + c * 8) = v;
        }
    }
    {
        const int row = t >> 2, f0 = (t & 3) * 32;
        const float* a1 = a + (size_t)hd * 2 * FOUT;
        const float* a2 = a1 + FOUT;
        float v1 = 0.f, v2 = 0.f;
#pragma unroll 8
        for (int fi = 0; fi < 32; ++fi) {
            float hv = sm.tr[row * PADK + f0 + fi];
            v1 += hv * a1[f0 + fi];
            v2 += hv * a2[f0 + fi];
        }
        v1 += __shfl_xor(v1, 1); v1 += __shfl_xor(v1, 2);
        v2 += __shfl_xor(v2, 1); v2 += __shfl_xor(v2, 2);
        if ((t & 3) == 0) {
            int bn = bn0 + row;
            s1[(size_t)bn * 8 + hd]          = v1;
            s2T[(size_t)hd * (B_ * N_) + bn] = v2;
        }
    }
}

// ---------------- K2: fused P-gen + MFMA PV, single-barrier, dbuf P+B, gll staging ---
// grid (N/32, H, B), block 256 (4 waves, each 16 rows x 64 cols)
#define LOADBS(j0, b0, b1, q0, q1) {                  \
    b0 = *(const float4*)&bm_row[(j0) + pj0];         \
    b1 = *(const float4*)&bm_row[(j0) + pj0 + 4];     \
    q0 = *(const float4*)&s2p[(j0) + pj0];            \
    q1 = *(const float4*)&s2p[(j0) + pj0 + 4];        \
}

__global__ __launch_bounds__(256, 4) void k_pv2(const unsigned short* __restrict__ hpT,
                                                const float* __restrict__ s1,
                                                const float* __restrict__ s2T,
                                                const float* __restrict__ biasm,
                                                float* __restrict__ out) {
    __shared__ __align__(16) unsigned short P[2][32][72];    // 9.2 KB
    __shared__ __align__(16) unsigned short Bl[2][128 * 64]; // 32 KB, swizzled chunks
    __shared__ float Zl[32];
    const int t    = threadIdx.x;
    const int lane = t & 63;
    const int wave = t >> 6;
    const int i0 = blockIdx.x * 32;
    const int hd = blockIdx.y;
    const int b  = blockIdx.z;

    const int prow = t >> 3;          // 0..31
    const int pj0  = (t & 7) * 8;     // 0..56
    const int gi   = (b << 10) + i0 + prow;
    const float s1v = s1[(size_t)gi * 8 + hd];
    const float* bm_row = biasm + (size_t)(i0 + prow) * N_;
    const float* s2p    = s2T + (size_t)hd * (B_ * N_) + (b << 10);

    const unsigned short* hpS = hpT + (size_t)(b * H_ + hd) * FOUT * N_;

    const int wr = (wave & 1) * 16;
    const int wc = (wave >> 1) * 64;
    const int arow = wr + (lane & 15);
    const int koff = (lane >> 4) * 8;

    f32x4 acc[4];
#pragma unroll
    for (int j = 0; j < 4; ++j) acc[j] = (f32x4){0.f, 0.f, 0.f, 0.f};
    float z_acc = 0.f;

    float4 bmA0, bmA1, svA0, svA1, bmB0, bmB1, svB0, svB1;

    // stage 64-j B tile (128 f-rows) into Bl[buf] via global_load_lds.
    // linear LDS dest (chunk c -> byte c*16); source pre-swizzled: col^ (row&7).
    auto stageB = [&](int j0, int buf) {
#pragma unroll
        for (int q = 0; q < 4; ++q) {
            const int c   = q * 256 + wave * 64 + lane;
            const int row = c >> 3;
            const int col = c & 7;
            const unsigned short* src = hpS + (size_t)row * N_ + j0 + ((col ^ (row & 7)) * 8);
            unsigned short* dst = &Bl[buf][(q * 256 + wave * 64) * 8];  // wave-uniform
            gll16(src, dst);
        }
    };

    auto pgen = [&](int buf, const float4& b0, const float4& b1,
                    const float4& q0, const float4& q1) {
        s16x8 pv;
        float x0 = s1v + q0.x; x0 = fmaxf(x0, NEG * x0) + b0.x;
        float x1 = s1v + q0.y; x1 = fmaxf(x1, NEG * x1) + b0.y;
        float x2 = s1v + q0.z; x2 = fmaxf(x2, NEG * x2) + b0.z;
        float x3 = s1v + q0.w; x3 = fmaxf(x3, NEG * x3) + b0.w;
        float x4 = s1v + q1.x; x4 = fmaxf(x4, NEG * x4) + b1.x;
        float x5 = s1v + q1.y; x5 = fmaxf(x5, NEG * x5) + b1.y;
        float x6 = s1v + q1.z; x6 = fmaxf(x6, NEG * x6) + b1.z;
        float x7 = s1v + q1.w; x7 = fmaxf(x7, NEG * x7) + b1.w;
        float p0 = __expf(x0), p1 = __expf(x1), p2 = __expf(x2), p3 = __expf(x3);
        float p4 = __expf(x4), p5 = __expf(x5), p6 = __expf(x6), p7 = __expf(x7);
        z_acc += ((p0 + p1) + (p2 + p3)) + ((p4 + p5) + (p6 + p7));
        pv[0] = (short)f2bf_hw(p0); pv[1] = (short)f2bf_hw(p1);
        pv[2] = (short)f2bf_hw(p2); pv[3] = (short)f2bf_hw(p3);
        pv[4] = (short)f2bf_hw(p4); pv[5] = (short)f2bf_hw(p5);
        pv[6] = (short)f2bf_hw(p6); pv[7] = (short)f2bf_hw(p7);
        *(s16x8*)&P[buf][prow][pj0] = pv;
    };

    auto mf = [&](int buf) {
#pragma unroll
        for (int kw = 0; kw < 2; ++kw) {
            s16x8 a0 = *(const s16x8*)&P[buf][arow][kw * 32 + koff];
#pragma unroll
            for (int fc = 0; fc < 4; ++fc) {
                const int r = wc + fc * 16 + (lane & 15);
                const int chunk = (lane >> 4) + kw * 4;
                s16x8 bf = *(const s16x8*)&Bl[buf][r * 64 + ((chunk ^ (r & 7)) * 8)];
                acc[fc] = __builtin_amdgcn_mfma_f32_16x16x32_bf16(a0, bf, acc[fc], 0, 0, 0);
            }
        }
    };

    // prologue: regs for tiles 0,1; B tile 0; P tile 0
    LOADBS(0,  bmA0, bmA1, svA0, svA1);
    LOADBS(64, bmB0, bmB1, svB0, svB1);
    stageB(0, 0);
    pgen(0, bmA0, bmA1, svA0, svA1);
    __syncthreads();   // drains gll(0) + P(0) writes

    // steady state: one barrier per iteration
#pragma unroll
    for (int it = 0; it < 16; ++it) {
        if ((it & 1) == 0) {
            if (it < 14) LOADBS((it + 2) * 64, bmA0, bmA1, svA0, svA1);
            if (it < 15) { stageB((it + 1) * 64, 1); pgen(1, bmB0, bmB1, svB0, svB1); }
            mf(0);
        } else {
            if (it < 14) LOADBS((it + 2) * 64, bmB0, bmB1, svB0, svB1);
            if (it < 15) { stageB((it + 1) * 64, 0); pgen(0, bmA0, bmA1, svA0, svA1); }
            mf(1);
        }
        __syncthreads();
    }

    // Z: reduce 8 lanes per row
    float z = z_acc;
    z += __shfl_xor(z, 1); z += __shfl_xor(z, 2); z += __shfl_xor(z, 4);
    if ((t & 7) == 0) Zl[prow] = 0.125f / z;   // folds softmax norm + head-mean
    __syncthreads();

    // epilogue: C/D layout col=lane&15, row=(lane>>4)*4+reg
#pragma unroll
    for (int r = 0; r < 4; ++r) {
        const int il = wr + (lane >> 4) * 4 + r;
        const float sc = Zl[il];
        float* op = out + ((size_t)((b << 10) + i0 + il)) * FOUT + wc + (lane & 15);
#pragma unroll
        for (int fc = 0; fc < 4; ++fc)
            unsafeAtomicAdd(op + fc * 16, acc[fc][r] * sc);
    }
}

extern "C" void kernel_launch(void* const* d_in, const int* in_sizes, int n_in,
                              void* d_out, int out_size, void* d_ws, size_t ws_size,
                              hipStream_t stream) {
    const float* hsrc = (const float*)d_in[0];
    const int*   adj  = (const int*)d_in[1];
    const float* bias = (const float*)d_in[2];
    const float* W    = (const float*)d_in[3];
    const float* a    = (const float*)d_in[4];
    float* out = (float*)d_out;

    char* ws = (char*)d_ws;
    unsigned short* hpT = (unsigned short*)ws;                 // 16 MB
    float* s1    = (float*)(ws + 16777216);                    // 256 KB
    float* s2T   = s1 + 65536;                                 // 256 KB
    float* biasm = s2T + 65536;                                // 4 MB
    unsigned short* WT = (unsigned short*)(biasm + N_ * N_);   // 256 KB

    hipMemsetAsync(d_out, 0, (size_t)out_size * sizeof(float), stream);
    k_bias<<<dim3(N_ * N_ / 1024), 256, 0, stream>>>(adj, bias, biasm);
    k_wt<<<dim3(H_), 256, 0, stream>>>(W, WT);
    k_hprime<<<dim3(B_ * N_ / 64, H_), 256, 0, stream>>>(hsrc, WT, a, hpT, s1, s2T);
    k_pv2<<<dim3(N_ / 32, H_, B_), 256, 0, stream>>>(hpT, s1, s2T, biasm, out);
}